// Round 1
// baseline (1063.638 us; speedup 1.0000x reference)
//
#include <hip/hip_runtime.h>
#include <math.h>

constexpr int H = 64;

// ---- CSR build ----
__global__ void k_hist(const int* __restrict__ dst, int* __restrict__ hist, int E) {
  int e = blockIdx.x * blockDim.x + threadIdx.x;
  if (e < E) atomicAdd(&hist[dst[e]], 1);
}

__global__ void k_scan(const int* __restrict__ hist, int* __restrict__ row_ptr,
                       int* __restrict__ pos, float* __restrict__ degf, int n) {
  __shared__ int sd[1024];
  __shared__ int s_off;
  int tid = threadIdx.x;
  if (tid == 0) { s_off = 0; row_ptr[0] = 0; }
  __syncthreads();
  for (int base = 0; base < n; base += 1024) {
    int i = base + tid;
    int v = (i < n) ? hist[i] : 0;
    sd[tid] = v;
    __syncthreads();
    for (int d = 1; d < 1024; d <<= 1) {
      int t = (tid >= d) ? sd[tid - d] : 0;
      __syncthreads();
      sd[tid] += t;
      __syncthreads();
    }
    int incl = sd[tid] + s_off;
    if (i < n) {
      row_ptr[i + 1] = incl;
      pos[i] = incl - v;
      degf[i] = (float)(v > 1 ? v : 1);
    }
    __syncthreads();
    if (tid == 1023) s_off = incl;
    __syncthreads();
  }
}

__global__ void k_scatter(const int* __restrict__ src, const int* __restrict__ dst,
                          const float* __restrict__ ea, int* __restrict__ pos,
                          int* __restrict__ ssrc, float* __restrict__ sea, int E) {
  int e = blockIdx.x * blockDim.x + threadIdx.x;
  if (e < E) {
    int d = dst[e];
    int p = atomicAdd(&pos[d], 1);
    ssrc[p] = src[e];
    sea[2 * p]     = ea[2 * e];
    sea[2 * p + 1] = ea[2 * e + 1];
  }
}

// ---- input projection: h = x @ W_in + b_in ----
__global__ void k_inproj(const float* __restrict__ x, const float* __restrict__ Win,
                         const float* __restrict__ bin, float* __restrict__ h, int n) {
  int t = blockIdx.x * blockDim.x + threadIdx.x;
  int v = t >> 6, j = t & 63;
  if (v < n) {
    float x0 = x[2 * v], x1 = x[2 * v + 1];
    h[(size_t)v * H + j] = fmaf(x0, Win[j], fmaf(x1, Win[H + j], bin[j]));
  }
}

// ---- g = h @ Wm1 (64x64), one wave per node ----
__global__ void k_gemm64(const float* __restrict__ h, const float* __restrict__ W,
                         float* __restrict__ g, int n) {
  __shared__ float sW[64 * 64];
  for (int i = threadIdx.x; i < 64 * 64; i += 256) sW[i] = W[i];
  __syncthreads();
  int v = blockIdx.x * 4 + (threadIdx.x >> 6);
  int j = threadIdx.x & 63;
  if (v >= n) return;
  float hv = h[(size_t)v * H + j];
  float acc = 0.f;
#pragma unroll
  for (int k = 0; k < 64; ++k)
    acc = fmaf(__shfl(hv, k), sW[k * 64 + j], acc);
  g[(size_t)v * H + j] = acc;
}

// ---- fused aggregate (CSR, no atomics) + update MLP, one wave per node ----
__global__ void k_aggupd(const float* __restrict__ g, const int* __restrict__ row_ptr,
                         const int* __restrict__ ssrc, const float* __restrict__ sea,
                         const float* __restrict__ degf,
                         const float* __restrict__ Wm, const float* __restrict__ bm,
                         const float* __restrict__ Wu, const float* __restrict__ bu,
                         float* __restrict__ h, int n) {
  __shared__ float sWu[128 * 64];  // 32 KB
  for (int i = threadIdx.x; i < 128 * 64; i += 256) sWu[i] = Wu[i];
  __syncthreads();
  int v = blockIdx.x * 4 + (threadIdx.x >> 6);
  int j = threadIdx.x & 63;
  if (v >= n) return;
  float w2a = Wm[64 * 64 + j], w2b = Wm[65 * 64 + j], bmj = bm[j];
  int beg = row_ptr[v], end = row_ptr[v + 1];
  float acc = 0.f;
  int i = beg;
  for (; i + 1 < end; i += 2) {
    int s0 = ssrc[i], s1 = ssrc[i + 1];
    float ga = g[(size_t)s0 * H + j], gb = g[(size_t)s1 * H + j];
    float e0a = sea[2 * i],     e1a = sea[2 * i + 1];
    float e0b = sea[2 * i + 2], e1b = sea[2 * i + 3];
    float va = fmaf(e0a, w2a, fmaf(e1a, w2b, ga + bmj));
    float vb = fmaf(e0b, w2a, fmaf(e1b, w2b, gb + bmj));
    acc += fmaxf(va, 0.f) + fmaxf(vb, 0.f);
  }
  if (i < end) {
    int s0 = ssrc[i];
    float va = fmaf(sea[2 * i], w2a, fmaf(sea[2 * i + 1], w2b, g[(size_t)s0 * H + j] + bmj));
    acc += fmaxf(va, 0.f);
  }
  acc /= degf[v];  // agg[v][j]
  float hv = h[(size_t)v * H + j];
  float out = bu[j];
#pragma unroll
  for (int k = 0; k < 64; ++k) {
    out = fmaf(__shfl(hv, k),  sWu[k * 64 + j],        out);
    out = fmaf(__shfl(acc, k), sWu[(64 + k) * 64 + j], out);
  }
  h[(size_t)v * H + j] = fmaxf(out, 0.f);
}

// ---- node head (sigmoid) + partial sums for global mean ----
__global__ void k_head(const float* __restrict__ h, const float* __restrict__ Wn,
                       const float* __restrict__ bn, float* __restrict__ probs,
                       float* __restrict__ part, int n) {
  int j = threadIdx.x & 63;
  int gw = blockIdx.x * (blockDim.x >> 6) + (threadIdx.x >> 6);
  int nw = gridDim.x * (blockDim.x >> 6);
  float wj = Wn[j], b0 = bn[0];
  float psum = 0.f;
  for (int v = gw; v < n; v += nw) {
    float hv = h[(size_t)v * H + j];
    psum += hv;
    float t = hv * wj;
#pragma unroll
    for (int d = 32; d > 0; d >>= 1) t += __shfl_down(t, d);
    if (j == 0) probs[v] = 1.f / (1.f + expf(-(t + b0)));
  }
  part[(size_t)gw * 64 + j] = psum;
}

// ---- global mean + 2-layer head ----
__global__ void k_final(const float* __restrict__ part, int nw,
                        const float* __restrict__ W1, const float* __restrict__ b1,
                        const float* __restrict__ W2, const float* __restrict__ b2,
                        float* __restrict__ out4, float n_nodes) {
  __shared__ float tmp[256];
  __shared__ float hmean[64];
  __shared__ float z1[32];
  int tid = threadIdx.x;
  int j = tid & 63, c = tid >> 6;
  float s = 0.f;
  for (int r = c; r < nw; r += 4) s += part[(size_t)r * 64 + j];
  tmp[tid] = s;
  __syncthreads();
  if (tid < 64)
    hmean[tid] = (tmp[tid] + tmp[tid + 64] + tmp[tid + 128] + tmp[tid + 192]) / n_nodes;
  __syncthreads();
  if (tid < 32) {
    float a = b1[tid];
    for (int k = 0; k < 64; ++k) a = fmaf(hmean[k], W1[k * 32 + tid], a);
    z1[tid] = fmaxf(a, 0.f);
  }
  __syncthreads();
  if (tid < 4) {
    float a = b2[tid];
    for (int k = 0; k < 32; ++k) a = fmaf(z1[k], W2[k * 4 + tid], a);
    out4[tid] = a;
  }
}

extern "C" void kernel_launch(void* const* d_in, const int* in_sizes, int n_in,
                              void* d_out, int out_size, void* d_ws, size_t ws_size,
                              hipStream_t stream) {
  const float* x    = (const float*)d_in[0];
  const int*   ei   = (const int*)d_in[1];
  const float* ea   = (const float*)d_in[2];
  const float* Win  = (const float*)d_in[3];
  const float* bin  = (const float*)d_in[4];
  const float* Wmsg = (const float*)d_in[5];
  const float* bmsg = (const float*)d_in[6];
  const float* Wupd = (const float*)d_in[7];
  const float* bupd = (const float*)d_in[8];
  const float* Wn   = (const float*)d_in[9];
  const float* bn   = (const float*)d_in[10];
  // d_in[11], d_in[12] (W_pool, b_pool) are unused by the reference output
  const float* W1   = (const float*)d_in[13];
  const float* b1   = (const float*)d_in[14];
  const float* W2   = (const float*)d_in[15];
  const float* b2   = (const float*)d_in[16];

  const int N = in_sizes[0] / 2;   // x is [N, 2]
  const int E = in_sizes[1] / 2;   // edge_index is [2, E]
  const int* src = ei;
  const int* dst = ei + E;

  char* ws = (char*)d_ws;
  size_t off = 0;
  auto alloc = [&](size_t bytes) {
    void* p = ws + off;
    off = (off + bytes + 255) & ~(size_t)255;
    return p;
  };
  int*   hist = (int*)  alloc((size_t)N * 4);
  int*   rptr = (int*)  alloc((size_t)(N + 1) * 4);
  int*   pos  = (int*)  alloc((size_t)N * 4);
  float* degf = (float*)alloc((size_t)N * 4);
  int*   ssrc = (int*)  alloc((size_t)E * 4);
  float* sea  = (float*)alloc((size_t)E * 8);
  float* g    = (float*)alloc((size_t)N * H * 4);
  float* part = (float*)alloc((size_t)4096 * 64 * 4);
  (void)ws_size;

  float* probs = (float*)d_out;          // [N]
  float* out4  = probs + N;              // [4]
  float* h     = out4 + 4;               // [N, 64]  (working buffer == output)

  hipMemsetAsync(hist, 0, (size_t)N * 4, stream);
  int eb = (E + 255) / 256;
  k_hist<<<eb, 256, 0, stream>>>(dst, hist, E);
  k_scan<<<1, 1024, 0, stream>>>(hist, rptr, pos, degf, N);
  k_scatter<<<eb, 256, 0, stream>>>(src, dst, ea, pos, ssrc, sea, E);

  int nb = (N + 3) / 4;  // one wave per node, 4 waves/block
  k_inproj<<<nb, 256, 0, stream>>>(x, Win, bin, h, N);

  for (int l = 0; l < 3; ++l) {
    k_gemm64<<<nb, 256, 0, stream>>>(h, Wmsg + (size_t)l * 66 * 64, g, N);
    k_aggupd<<<nb, 256, 0, stream>>>(g, rptr, ssrc, sea, degf,
                                     Wmsg + (size_t)l * 66 * 64, bmsg + (size_t)l * 64,
                                     Wupd + (size_t)l * 128 * 64, bupd + (size_t)l * 64,
                                     h, N);
  }

  k_head<<<1024, 256, 0, stream>>>(h, Wn, bn, probs, part, N);
  k_final<<<1, 256, 0, stream>>>(part, 4096, W1, b1, W2, b2, out4, (float)N);
}